// Round 15
// baseline (130.600 us; speedup 1.0000x reference)
//
#include <hip/hip_runtime.h>
#include <hip/hip_bf16.h>

#define IN_SIZE 65536
#define HIDDEN 128
#define D_STEPS 64
#define N_ACT 512

typedef _Float16 half2_ __attribute__((ext_vector_type(2)));
typedef _Float16 half4_ __attribute__((ext_vector_type(4)));
typedef _Float16 half8_ __attribute__((ext_vector_type(8)));
typedef float f32x4 __attribute__((ext_vector_type(4)));

// ---------------- Kernel A: ihx partials (UNCHANGED from R9) ----------------
__global__ __launch_bounds__(256) void k_ihx(const float* __restrict__ w_ih,
                                             const float* __restrict__ x,
                                             float* __restrict__ partials) {
    int bid = blockIdx.x;
    int rp = bid >> 3;       // row pair 0..255
    int ck = bid & 7;        // chunk 0..7 (8192 cols each)
    int t = threadIdx.x;
    int r0 = 2 * rp, r1 = 2 * rp + 1;
    const float4* xp = (const float4*)(x + ck * 8192);
    const float4* w0 = (const float4*)(w_ih + (size_t)r0 * IN_SIZE + ck * 8192);
    const float4* w1 = (const float4*)(w_ih + (size_t)r1 * IN_SIZE + ck * 8192);

    float4 xv[8];
#pragma unroll
    for (int i = 0; i < 8; ++i) xv[i] = xp[t + i * 256];

    float a0 = 0.f, a1 = 0.f;
#pragma unroll
    for (int i = 0; i < 8; ++i) {
        float4 w4 = w0[t + i * 256];
        a0 += w4.x * xv[i].x + w4.y * xv[i].y + w4.z * xv[i].z + w4.w * xv[i].w;
    }
#pragma unroll
    for (int i = 0; i < 8; ++i) {
        float4 w4 = w1[t + i * 256];
        a1 += w4.x * xv[i].x + w4.y * xv[i].y + w4.z * xv[i].z + w4.w * xv[i].w;
    }
#pragma unroll
    for (int off = 32; off; off >>= 1) {
        a0 += __shfl_down(a0, off, 64);
        a1 += __shfl_down(a1, off, 64);
    }
    __shared__ float s[8];
    if ((t & 63) == 0) { s[t >> 6] = a0; s[4 + (t >> 6)] = a1; }
    __syncthreads();
    if (t == 0) {
        partials[r0 * 8 + ck] = s[0] + s[1] + s[2] + s[3];
        partials[r1 * 8 + ck] = s[4] + s[5] + s[6] + s[7];
    }
}

// ---------- Kernel B: MFMA recurrence + logits (64 blocks, redundant rec) ----
// R14 diagnosis: VGPR_Count=88 < afrag's 64+needs -> LLVM rematerialized the
// loop-invariant afrag LDS loads INSIDE the loop: 8 waves x ~24 ds_read_b128
// per step ~ 2300 cyc/step on the one LDS pipe (MfmaUtil 2.8%, VALU 16% idle).
// Fix: asm-volatile output pin on afrag + ihx vectors -> cannot be remat'd
// from memory -> forced live in VGPRs across the loop. Steady state: 4 bf
// ds_reads + 1 h write per wave per step.
__global__ __attribute__((amdgpu_flat_work_group_size(512, 512)))
__attribute__((amdgpu_waves_per_eu(2, 2)))
void k_rec_logits(
    const float* __restrict__ w_hh,
    const float* __restrict__ b_ih,
    const float* __restrict__ b_hh,
    const float* __restrict__ w_lin,
    const float* __restrict__ b_lin,
    const float* __restrict__ partials,
    float* __restrict__ out) {
    int t = threadIdx.x;
    int b = blockIdx.x;      // 0..63: which step this block's logits cover
    int w = t >> 6;          // wave 0..7
    int l = t & 63;
    int lg = l >> 4;         // lane group 0..3
    int lm = l & 15;

    __shared__ _Float16 whh_s[4 * HIDDEN * HIDDEN];  // 128 KB, f16 w_hh
    __shared__ half8_ h_v[2][16];                    // h, double-buffered
    __shared__ float h_keep[HIDDEN];
    __shared__ float ihx_s[4 * HIDDEN];              // 2 KB

    // ---- stage w_hh -> LDS as f16 (coalesced float2 stream, low pressure) ----
    {
        const float2* src = (const float2*)w_hh;     // 32768 float2
        half2_* dst = (half2_*)whh_s;
#pragma unroll 4
        for (int i = 0; i < 64; ++i) {
            float2 v = src[i * 512 + t];
            half2_ p = {(_Float16)v.x, (_Float16)v.y};
            dst[i * 512 + t] = p;
        }
    }
    // ---- ihx -> LDS (thread t owns row t) ----
    {
        const float4* pp = (const float4*)(partials + t * 8);
        float4 p0 = pp[0], p1 = pp[1];
        ihx_s[t] = p0.x + p0.y + p0.z + p0.w + p1.x + p1.y + p1.z + p1.w +
                   b_ih[t] + b_hh[t];
    }
    if (t < 16) {
        half8_ z = {(_Float16)0.f, (_Float16)0.f, (_Float16)0.f, (_Float16)0.f,
                    (_Float16)0.f, (_Float16)0.f, (_Float16)0.f, (_Float16)0.f};
        h_v[0][t] = z;
    }
    __syncthreads();

    // ---- fill afrag + ihx vectors ONCE, then pin in VGPRs via asm output ----
    half8_ afrag[4][4];
#pragma unroll
    for (int G = 0; G < 4; ++G) {
#pragma unroll
        for (int kt = 0; kt < 4; ++kt) {
            afrag[G][kt] = *(const half8_*)&whh_s[(size_t)(G * HIDDEN + 16 * w + lm) * HIDDEN
                                                  + kt * 32 + lg * 8];
        }
    }
    f32x4 ihxv[4];
#pragma unroll
    for (int G = 0; G < 4; ++G)
        ihxv[G] = *(const f32x4*)&ihx_s[G * HIDDEN + 16 * w + lg * 4];

    // Pin: values become asm-volatile outputs -> LLVM cannot rematerialize
    // them by re-reading LDS inside the loop; they stay resident in VGPRs.
    asm volatile(""
        : "+v"(afrag[0][0]), "+v"(afrag[0][1]), "+v"(afrag[0][2]), "+v"(afrag[0][3]),
          "+v"(afrag[1][0]), "+v"(afrag[1][1]), "+v"(afrag[1][2]), "+v"(afrag[1][3]),
          "+v"(afrag[2][0]), "+v"(afrag[2][1]), "+v"(afrag[2][2]), "+v"(afrag[2][3]),
          "+v"(afrag[3][0]), "+v"(afrag[3][1]), "+v"(afrag[3][2]), "+v"(afrag[3][3]),
          "+v"(ihxv[0]), "+v"(ihxv[1]), "+v"(ihxv[2]), "+v"(ihxv[3]));

    float c[4] = {0.f, 0.f, 0.f, 0.f};   // static-indexed (registers)
    for (int d = 0; d < D_STEPS; ++d) {
        int rb = d & 1, wb = rb ^ 1;
        // B fragments: lane needs h[kt*32 + lg*8 .. +7] -> ds_read_b128,
        // 4 distinct addrs/wave (broadcast, conflict-free)
        half8_ bf0 = h_v[rb][0 * 4 + lg];
        half8_ bf1 = h_v[rb][1 * 4 + lg];
        half8_ bf2 = h_v[rb][2 * 4 + lg];
        half8_ bf3 = h_v[rb][3 * 4 + lg];
        f32x4 ai_ = ihxv[0];
        f32x4 af_ = ihxv[1];
        f32x4 ag_ = ihxv[2];
        f32x4 ao_ = ihxv[3];
#define MFMA __builtin_amdgcn_mfma_f32_16x16x32_f16
        ai_ = MFMA(afrag[0][0], bf0, ai_, 0, 0, 0);
        af_ = MFMA(afrag[1][0], bf0, af_, 0, 0, 0);
        ag_ = MFMA(afrag[2][0], bf0, ag_, 0, 0, 0);
        ao_ = MFMA(afrag[3][0], bf0, ao_, 0, 0, 0);
        ai_ = MFMA(afrag[0][1], bf1, ai_, 0, 0, 0);
        af_ = MFMA(afrag[1][1], bf1, af_, 0, 0, 0);
        ag_ = MFMA(afrag[2][1], bf1, ag_, 0, 0, 0);
        ao_ = MFMA(afrag[3][1], bf1, ao_, 0, 0, 0);
        ai_ = MFMA(afrag[0][2], bf2, ai_, 0, 0, 0);
        af_ = MFMA(afrag[1][2], bf2, af_, 0, 0, 0);
        ag_ = MFMA(afrag[2][2], bf2, ag_, 0, 0, 0);
        ao_ = MFMA(afrag[3][2], bf2, ao_, 0, 0, 0);
        ai_ = MFMA(afrag[0][3], bf3, ai_, 0, 0, 0);
        af_ = MFMA(afrag[1][3], bf3, af_, 0, 0, 0);
        ag_ = MFMA(afrag[2][3], bf3, ag_, 0, 0, 0);
        ao_ = MFMA(afrag[3][3], bf3, ao_, 0, 0, 0);
#undef MFMA
        // activations: all 4 gates in-lane; 16 redundant lanes -> deterministic
        float hv[4];
#pragma unroll
        for (int r = 0; r < 4; ++r) {
            float ig = 1.f / (1.f + __expf(-ai_[r]));
            float fg = 1.f / (1.f + __expf(-af_[r]));
            float gg = 2.f / (1.f + __expf(-2.f * ag_[r])) - 1.f;
            float og = 1.f / (1.f + __expf(-ao_[r]));
            float cn = fg * c[r] + ig * gg;
            c[r] = cn;
            hv[r] = og * (2.f / (1.f + __expf(-2.f * cn)) - 1.f);
        }
        if (lm == 0) {
            half4_ hp = {(_Float16)hv[0], (_Float16)hv[1],
                         (_Float16)hv[2], (_Float16)hv[3]};
            *(half4_*)((char*)(&h_v[wb][0]) + (size_t)(16 * w + lg * 4) * 2) = hp;
            if (d == b) {
                int cb = 16 * w + lg * 4;
                h_keep[cb + 0] = hv[0]; h_keep[cb + 1] = hv[1];
                h_keep[cb + 2] = hv[2]; h_keep[cb + 3] = hv[3];
            }
        }
        __syncthreads();
    }

    // ---- logits for step d = b from h_keep ----
    {
        const float4* wl = (const float4*)(w_lin + (size_t)t * HIDDEN);
        float acc = b_lin[t];
#pragma unroll
        for (int k = 0; k < HIDDEN / 4; ++k) {
            float4 w4 = wl[k];
            acc += w4.x * h_keep[4 * k + 0] + w4.y * h_keep[4 * k + 1] +
                   w4.z * h_keep[4 * k + 2] + w4.w * h_keep[4 * k + 3];
        }
        out[b * N_ACT + t] = acc;
    }
}

extern "C" void kernel_launch(void* const* d_in, const int* in_sizes, int n_in,
                              void* d_out, int out_size, void* d_ws, size_t ws_size,
                              hipStream_t stream) {
    const float* x     = (const float*)d_in[0];
    const float* w_ih  = (const float*)d_in[1];
    const float* w_hh  = (const float*)d_in[2];
    const float* b_ih  = (const float*)d_in[3];
    const float* b_hh  = (const float*)d_in[4];
    const float* w_lin = (const float*)d_in[5];
    const float* b_lin = (const float*)d_in[6];
    float* out = (float*)d_out;

    float* partials = (float*)d_ws;      // 4096 floats

    k_ihx<<<2048, 256, 0, stream>>>(w_ih, x, partials);
    k_rec_logits<<<D_STEPS, 512, 0, stream>>>(w_hh, b_ih, b_hh, w_lin, b_lin,
                                              partials, out);
}

// Round 16
// 69.685 us; speedup vs baseline: 1.8741x; 1.8741x over previous
//
#include <hip/hip_runtime.h>
#include <hip/hip_bf16.h>

#define IN_SIZE 65536
#define HIDDEN 128
#define D_STEPS 64
#define N_ACT 512

typedef _Float16 half2_ __attribute__((ext_vector_type(2)));
typedef _Float16 half4_ __attribute__((ext_vector_type(4)));
typedef _Float16 half8_ __attribute__((ext_vector_type(8)));
typedef float f32x4 __attribute__((ext_vector_type(4)));

__device__ __forceinline__ float rcp_(float x) {
#if __has_builtin(__builtin_amdgcn_rcpf)
    return __builtin_amdgcn_rcpf(x);   // v_rcp_f32 (~1 ulp)
#else
    return 1.f / x;
#endif
}
__device__ __forceinline__ float exp2_(float x) {
#if __has_builtin(__builtin_amdgcn_exp2f)
    return __builtin_amdgcn_exp2f(x);  // v_exp_f32
#else
    return __exp2f(x);
#endif
}
#define L2E 1.44269504088896340736f

// ---------------- Kernel A: ihx partials (UNCHANGED from R9) ----------------
__global__ __launch_bounds__(256) void k_ihx(const float* __restrict__ w_ih,
                                             const float* __restrict__ x,
                                             float* __restrict__ partials) {
    int bid = blockIdx.x;
    int rp = bid >> 3;       // row pair 0..255
    int ck = bid & 7;        // chunk 0..7 (8192 cols each)
    int t = threadIdx.x;
    int r0 = 2 * rp, r1 = 2 * rp + 1;
    const float4* xp = (const float4*)(x + ck * 8192);
    const float4* w0 = (const float4*)(w_ih + (size_t)r0 * IN_SIZE + ck * 8192);
    const float4* w1 = (const float4*)(w_ih + (size_t)r1 * IN_SIZE + ck * 8192);

    float4 xv[8];
#pragma unroll
    for (int i = 0; i < 8; ++i) xv[i] = xp[t + i * 256];

    float a0 = 0.f, a1 = 0.f;
#pragma unroll
    for (int i = 0; i < 8; ++i) {
        float4 w4 = w0[t + i * 256];
        a0 += w4.x * xv[i].x + w4.y * xv[i].y + w4.z * xv[i].z + w4.w * xv[i].w;
    }
#pragma unroll
    for (int i = 0; i < 8; ++i) {
        float4 w4 = w1[t + i * 256];
        a1 += w4.x * xv[i].x + w4.y * xv[i].y + w4.z * xv[i].z + w4.w * xv[i].w;
    }
#pragma unroll
    for (int off = 32; off; off >>= 1) {
        a0 += __shfl_down(a0, off, 64);
        a1 += __shfl_down(a1, off, 64);
    }
    __shared__ float s[8];
    if ((t & 63) == 0) { s[t >> 6] = a0; s[4 + (t >> 6)] = a1; }
    __syncthreads();
    if (t == 0) {
        partials[r0 * 8 + ck] = s[0] + s[1] + s[2] + s[3];
        partials[r1 * 8 + ck] = s[4] + s[5] + s[6] + s[7];
    }
}

// ---------- Kernel B: MFMA recurrence + logits (64 blocks, redundant rec) ----
// R15 diagnosis: loop is ACTIVATION-VALU-bound (~2550 VALU cyc/SIMD/step):
// 20 f32 divisions/thread/step each lowering to ~12-instr div sequences, x4
// unrolled r. Fixes: (a) v_rcp_f32 + v_exp_f32 directly (1 instr each);
// (b) lane-split: lane lm computes only cell r=lm&3 (12 cndmask select) ->
// activation sequence issues ONCE per wave instead of 4x. h written by
// lanes lm<4 as b16. Math identical (redundant lanes agree) -> deterministic.
__global__ __attribute__((amdgpu_flat_work_group_size(512, 512)))
__attribute__((amdgpu_waves_per_eu(2, 2)))
void k_rec_logits(
    const float* __restrict__ w_hh,
    const float* __restrict__ b_ih,
    const float* __restrict__ b_hh,
    const float* __restrict__ w_lin,
    const float* __restrict__ b_lin,
    const float* __restrict__ partials,
    float* __restrict__ out) {
    int t = threadIdx.x;
    int b = blockIdx.x;      // 0..63: which step this block's logits cover
    int w = t >> 6;          // wave 0..7
    int l = t & 63;
    int lg = l >> 4;         // lane group 0..3
    int lm = l & 15;

    __shared__ _Float16 whh_s[4 * HIDDEN * HIDDEN];  // 128 KB, f16 w_hh
    __shared__ half8_ h_v[2][16];                    // h, double-buffered
    __shared__ float h_keep[HIDDEN];
    __shared__ float ihx_s[4 * HIDDEN];              // 2 KB

    // ---- stage w_hh -> LDS as f16 (coalesced float2 stream) ----
    {
        const float2* src = (const float2*)w_hh;     // 32768 float2
        half2_* dst = (half2_*)whh_s;
#pragma unroll 4
        for (int i = 0; i < 64; ++i) {
            float2 v = src[i * 512 + t];
            half2_ p = {(_Float16)v.x, (_Float16)v.y};
            dst[i * 512 + t] = p;
        }
    }
    // ---- ihx -> LDS (thread t owns row t) ----
    {
        const float4* pp = (const float4*)(partials + t * 8);
        float4 p0 = pp[0], p1 = pp[1];
        ihx_s[t] = p0.x + p0.y + p0.z + p0.w + p1.x + p1.y + p1.z + p1.w +
                   b_ih[t] + b_hh[t];
    }
    if (t < 16) {
        half8_ z = {(_Float16)0.f, (_Float16)0.f, (_Float16)0.f, (_Float16)0.f,
                    (_Float16)0.f, (_Float16)0.f, (_Float16)0.f, (_Float16)0.f};
        h_v[0][t] = z;
    }
    __syncthreads();

    // ---- fill afrag + ihx vectors ONCE, pin in VGPRs ----
    half8_ afrag[4][4];
#pragma unroll
    for (int G = 0; G < 4; ++G) {
#pragma unroll
        for (int kt = 0; kt < 4; ++kt) {
            afrag[G][kt] = *(const half8_*)&whh_s[(size_t)(G * HIDDEN + 16 * w + lm) * HIDDEN
                                                  + kt * 32 + lg * 8];
        }
    }
    f32x4 ihxv[4];
#pragma unroll
    for (int G = 0; G < 4; ++G)
        ihxv[G] = *(const f32x4*)&ihx_s[G * HIDDEN + 16 * w + lg * 4];

    asm volatile(""
        : "+v"(afrag[0][0]), "+v"(afrag[0][1]), "+v"(afrag[0][2]), "+v"(afrag[0][3]),
          "+v"(afrag[1][0]), "+v"(afrag[1][1]), "+v"(afrag[1][2]), "+v"(afrag[1][3]),
          "+v"(afrag[2][0]), "+v"(afrag[2][1]), "+v"(afrag[2][2]), "+v"(afrag[2][3]),
          "+v"(afrag[3][0]), "+v"(afrag[3][1]), "+v"(afrag[3][2]), "+v"(afrag[3][3]),
          "+v"(ihxv[0]), "+v"(ihxv[1]), "+v"(ihxv[2]), "+v"(ihxv[3]));

    // lane's cell for activation: r2 = lm & 3 ; selection predicates
    int r2 = lm & 3;
    bool s1 = (r2 & 1) != 0, s2 = (r2 & 2) != 0;
    float c_own = 0.f;                  // cell state for cell 16w + lg*4 + r2

    for (int d = 0; d < D_STEPS; ++d) {
        int rb = d & 1, wb = rb ^ 1;
        // B fragments: broadcast ds_read_b128 (4 distinct addrs/wave)
        half8_ bf0 = h_v[rb][0 * 4 + lg];
        half8_ bf1 = h_v[rb][1 * 4 + lg];
        half8_ bf2 = h_v[rb][2 * 4 + lg];
        half8_ bf3 = h_v[rb][3 * 4 + lg];
        f32x4 ai_ = ihxv[0];
        f32x4 af_ = ihxv[1];
        f32x4 ag_ = ihxv[2];
        f32x4 ao_ = ihxv[3];
#define MFMA __builtin_amdgcn_mfma_f32_16x16x32_f16
        ai_ = MFMA(afrag[0][0], bf0, ai_, 0, 0, 0);
        af_ = MFMA(afrag[1][0], bf0, af_, 0, 0, 0);
        ag_ = MFMA(afrag[2][0], bf0, ag_, 0, 0, 0);
        ao_ = MFMA(afrag[3][0], bf0, ao_, 0, 0, 0);
        ai_ = MFMA(afrag[0][1], bf1, ai_, 0, 0, 0);
        af_ = MFMA(afrag[1][1], bf1, af_, 0, 0, 0);
        ag_ = MFMA(afrag[2][1], bf1, ag_, 0, 0, 0);
        ao_ = MFMA(afrag[3][1], bf1, ao_, 0, 0, 0);
        ai_ = MFMA(afrag[0][2], bf2, ai_, 0, 0, 0);
        af_ = MFMA(afrag[1][2], bf2, af_, 0, 0, 0);
        ag_ = MFMA(afrag[2][2], bf2, ag_, 0, 0, 0);
        ao_ = MFMA(afrag[3][2], bf2, ao_, 0, 0, 0);
        ai_ = MFMA(afrag[0][3], bf3, ai_, 0, 0, 0);
        af_ = MFMA(afrag[1][3], bf3, af_, 0, 0, 0);
        ag_ = MFMA(afrag[2][3], bf3, ag_, 0, 0, 0);
        ao_ = MFMA(afrag[3][3], bf3, ao_, 0, 0, 0);
#undef MFMA
        // select this lane's cell from the f32x4 accs (constant-index + cndmask)
        float gi = s2 ? (s1 ? ai_[3] : ai_[2]) : (s1 ? ai_[1] : ai_[0]);
        float gf = s2 ? (s1 ? af_[3] : af_[2]) : (s1 ? af_[1] : af_[0]);
        float gg = s2 ? (s1 ? ag_[3] : ag_[2]) : (s1 ? ag_[1] : ag_[0]);
        float go = s2 ? (s1 ? ao_[3] : ao_[2]) : (s1 ? ao_[1] : ao_[0]);
        // activations: 5 exp2 + 5 rcp + ~10 VALU, issued ONCE per wave
        float ig = rcp_(1.f + exp2_(-L2E * gi));
        float fg = rcp_(1.f + exp2_(-L2E * gf));
        float gt = 2.f * rcp_(1.f + exp2_(-2.f * L2E * gg)) - 1.f;
        float og = rcp_(1.f + exp2_(-L2E * go));
        c_own = fg * c_own + ig * gt;
        float th = 2.f * rcp_(1.f + exp2_(-2.f * L2E * c_own)) - 1.f;
        float h = og * th;
        if (lm < 4) {                       // lm == r2 here
            int cell = 16 * w + lg * 4 + r2;
            ((_Float16*)&h_v[wb][0])[cell] = (_Float16)h;
            if (d == b) h_keep[cell] = h;
        }
        __syncthreads();
    }

    // ---- logits for step d = b from h_keep ----
    {
        const float4* wl = (const float4*)(w_lin + (size_t)t * HIDDEN);
        float acc = b_lin[t];
#pragma unroll
        for (int k = 0; k < HIDDEN / 4; ++k) {
            float4 w4 = wl[k];
            acc += w4.x * h_keep[4 * k + 0] + w4.y * h_keep[4 * k + 1] +
                   w4.z * h_keep[4 * k + 2] + w4.w * h_keep[4 * k + 3];
        }
        out[b * N_ACT + t] = acc;
    }
}

extern "C" void kernel_launch(void* const* d_in, const int* in_sizes, int n_in,
                              void* d_out, int out_size, void* d_ws, size_t ws_size,
                              hipStream_t stream) {
    const float* x     = (const float*)d_in[0];
    const float* w_ih  = (const float*)d_in[1];
    const float* w_hh  = (const float*)d_in[2];
    const float* b_ih  = (const float*)d_in[3];
    const float* b_hh  = (const float*)d_in[4];
    const float* w_lin = (const float*)d_in[5];
    const float* b_lin = (const float*)d_in[6];
    float* out = (float*)d_out;

    float* partials = (float*)d_ws;      // 4096 floats

    k_ihx<<<2048, 256, 0, stream>>>(w_ih, x, partials);
    k_rec_logits<<<D_STEPS, 512, 0, stream>>>(w_hh, b_ih, b_hh, w_lin, b_lin,
                                              partials, out);
}